// Round 5
// baseline (2766.057 us; speedup 1.0000x reference)
//
#include <hip/hip_runtime.h>
#include <stdint.h>

#define HDIM 128
#define NGRID 262144
#define NMESH 40962
#define NEDGE 524288

typedef __attribute__((ext_vector_type(8))) short short8;
typedef __attribute__((ext_vector_type(16))) float f32x16;
typedef unsigned int u32;
typedef unsigned long long u64;

// ---- ws layout (byte offsets) ----
#define WS_COUNT   0x000000u
#define WS_ROWPTR  0x100000u
#define WS_WLOC    0x200010u
#define WS_BSUM    0x300100u
#define WS_SORTED  0x310000u
#define WS_WEIGHTS 0x800000u
// weight section offsets in u16 units:
#define WE1 0u
#define WE2 49152u
#define WN1 65536u
#define WN2 98304u

static __device__ __forceinline__ u32 f2bf_u(float f) {
  union { float f; u32 u; } v; v.f = f;
  u32 u = v.u;
  u += 0x7fffu + ((u >> 16) & 1u);
  return u >> 16;
}
static __device__ __forceinline__ unsigned short f2bf(float f) { return (unsigned short)f2bf_u(f); }
static __device__ __forceinline__ u32 pack2bf(float a, float b) {
  return f2bf_u(a) | (f2bf_u(b) << 16);
}
static __device__ __forceinline__ short8 cvt8(const float* p) {
  float4 f0 = *(const float4*)p;
  float4 f1 = *(const float4*)(p + 4);
  short8 r;
  r[0] = (short)f2bf_u(f0.x); r[1] = (short)f2bf_u(f0.y);
  r[2] = (short)f2bf_u(f0.z); r[3] = (short)f2bf_u(f0.w);
  r[4] = (short)f2bf_u(f1.x); r[5] = (short)f2bf_u(f1.y);
  r[6] = (short)f2bf_u(f1.z); r[7] = (short)f2bf_u(f1.w);
  return r;
}

union U8 { unsigned int u[4]; short8 s; };

// ---- pack weights frag-major for 32x32x16: frag (w,ks), lane-contiguous 16B ----
__global__ void pack_weights(const float* __restrict__ eW1, const float* __restrict__ eW2,
                             const float* __restrict__ nW1, const float* __restrict__ nW2,
                             unsigned short* __restrict__ wp)
{
  int i = blockIdx.x * 256 + threadIdx.x;
  const float* W; int KS; u32 base; int j;
  if (i < 49152)       { W = eW1; KS = 24; base = WE1; j = i; }
  else if (i < 65536)  { W = eW2; KS = 8;  base = WE2; j = i - 49152; }
  else if (i < 98304)  { W = nW1; KS = 16; base = WN1; j = i - 65536; }
  else if (i < 114688) { W = nW2; KS = 8;  base = WN2; j = i - 98304; }
  else return;
  int ii = j & 7, l = (j >> 3) & 63, frag = j >> 9;
  int ks = frag % KS, w = frag / KS;
  int row = w * 32 + (l & 31);
  int k = ks * 16 + (l >> 5) * 8 + ii;
  wp[base + j] = f2bf(W[(size_t)k * 128 + row]);
}

__global__ void hist_k(const int* __restrict__ dst, u32* __restrict__ cnt) {
  int e = blockIdx.x * 256 + threadIdx.x;
  atomicAdd(&cnt[dst[e]], 1u);
}

__global__ void scan1(const u32* __restrict__ cnt, u32* __restrict__ rp, u32* __restrict__ bsum) {
  int t = threadIdx.x, b = blockIdx.x;
  int i0 = b * 1024 + t * 4;
  uint4 v = *(const uint4*)(cnt + i0);
  u32 s = v.x + v.y + v.z + v.w;
  u32 sc = s;
  #pragma unroll
  for (int d = 1; d < 64; d <<= 1) {
    u32 n = (u32)__shfl_up((int)sc, d);
    if ((t & 63) >= d) sc += n;
  }
  __shared__ u32 wsum[4];
  if ((t & 63) == 63) wsum[t >> 6] = sc;
  __syncthreads();
  u32 woff = 0;
  for (int w = 0; w < (t >> 6); ++w) woff += wsum[w];
  u32 ex = woff + sc - s;
  rp[i0] = ex; rp[i0 + 1] = ex + v.x; rp[i0 + 2] = ex + v.x + v.y; rp[i0 + 3] = ex + v.x + v.y + v.z;
  if (t == 255) bsum[b] = woff + sc;
}

__global__ void scan2(u32* __restrict__ bsum) {
  int t = threadIdx.x;
  u32 s = bsum[t];
  u32 sc = s;
  #pragma unroll
  for (int d = 1; d < 64; d <<= 1) {
    u32 n = (u32)__shfl_up((int)sc, d);
    if ((t & 63) >= d) sc += n;
  }
  __shared__ u32 wsum[4];
  if ((t & 63) == 63) wsum[t >> 6] = sc;
  __syncthreads();
  u32 woff = 0;
  for (int w = 0; w < (t >> 6); ++w) woff += wsum[w];
  bsum[t] = woff + sc - s;
}

__global__ void scan3(u32* __restrict__ rp, u32* __restrict__ wloc, const u32* __restrict__ bsum) {
  int t = threadIdx.x, b = blockIdx.x;
  int i0 = b * 1024 + t * 4;
  u32 off = bsum[b];
  #pragma unroll
  for (int j = 0; j < 4; ++j) { u32 vv = rp[i0 + j] + off; rp[i0 + j] = vv; wloc[i0 + j] = vv; }
  if (b == 0 && t == 0) rp[NGRID] = NEDGE;
}

__global__ void scatter_k(const int* __restrict__ src, const int* __restrict__ dst,
                          u32* __restrict__ wloc, u64* __restrict__ sorted) {
  int e = blockIdx.x * 256 + threadIdx.x;
  int d = dst[e];
  u32 pos = atomicAdd(&wloc[d], 1u);
  sorted[pos] = (u64)(u32)src[e] | ((u64)(u32)d << 16) | ((u64)(u32)e << 34);
}

// ---- fused: block = 32 grid nodes; each wave owns 32-edge tiles (barrier-free edge loop) ----
__global__ __launch_bounds__(256, 4)
void fused_kernel(const float* __restrict__ ef, const float* __restrict__ gridf,
                  const float* __restrict__ mesh,
                  const unsigned short* __restrict__ wp,
                  const float* __restrict__ eb1, const float* __restrict__ eb2,
                  const float* __restrict__ elng, const float* __restrict__ elnb,
                  const float* __restrict__ nb1, const float* __restrict__ nb2,
                  const float* __restrict__ nlng, const float* __restrict__ nlnb,
                  const u32* __restrict__ rowptr, const u64* __restrict__ sorted,
                  float* __restrict__ out)
{
  __shared__ float aggLDS[32 * 129];   // 16.5 KB, stride-129: conflict-free scalar access

  const int tid = threadIdx.x;
  const int wv = tid >> 6, ln = tid & 63, l31 = ln & 31, hi = ln >> 5;
  const int n0 = blockIdx.x * 32;
  const int rs = (int)rowptr[n0], re = (int)rowptr[n0 + 32];

  for (int i = tid; i < 32 * 129; i += 256) aggLDS[i] = 0.f;
  __syncthreads();

  const short8* A1 = (const short8*)(wp + WE1);
  const short8* A2 = (const short8*)(wp + WE2);

  // -------- edge loop: wave-private tiles, no barriers --------
  for (int base = rs + wv * 32; base < re; base += 128) {
    int p = base + l31;
    const bool valid = p < re;
    if (!valid) p = re - 1;
    const u64 sv = sorted[p];
    const int dl = (int)((sv >> 16) & 0x3ffffu) - n0;
    const float* rowS = mesh  + (size_t)(sv & 0xffffu) * HDIM;
    const float* rowD = gridf + (size_t)(n0 + dl) * HDIM;
    const float* rowE = ef    + (size_t)(sv >> 34) * HDIM;

    // GEMM1: h1[128 cols x 32 edges], K=384, 4 independent chains
    f32x16 a1[4];
    #pragma unroll
    for (int c = 0; c < 4; ++c) a1[c] = (f32x16)(0.f);
    #pragma unroll
    for (int ks = 0; ks < 24; ++ks) {
      const float* bp = (ks < 8) ? (rowS + ks * 16)
                      : (ks < 16) ? (rowD + (ks - 8) * 16)
                                  : (rowE + (ks - 16) * 16);
      short8 B = cvt8(bp + hi * 8);
      #pragma unroll
      for (int c = 0; c < 4; ++c)
        a1[c] = __builtin_amdgcn_mfma_f32_32x32x16_bf16(A1[(c * 24 + ks) * 64 + ln], B, a1[c], 0, 0, 0);
    }

    // silu(x+b1) then pack to GEMM2 B-frags (in-register, shfl pair-exchange)
    U8 B2[8];
    #pragma unroll
    for (int c = 0; c < 4; ++c) {
      #pragma unroll
      for (int q = 0; q < 4; ++q) {
        float4 b1q = *(const float4*)(eb1 + 32 * c + 8 * q + 4 * hi);
        #pragma unroll
        for (int i = 0; i < 4; ++i) {
          float x = a1[c][q * 4 + i] + b1q[i];
          a1[c][q * 4 + i] = x / (1.f + __expf(-x));
        }
      }
      #pragma unroll
      for (int h = 0; h < 2; ++h) {
        const f32x16& a = a1[c];
        unsigned P1a = pack2bf(a[8 * h + 0], a[8 * h + 1]);
        unsigned P1b = pack2bf(a[8 * h + 2], a[8 * h + 3]);
        unsigned P2a = pack2bf(a[8 * h + 4], a[8 * h + 5]);
        unsigned P2b = pack2bf(a[8 * h + 6], a[8 * h + 7]);
        unsigned sA = hi ? P1a : P2a, sB = hi ? P1b : P2b;
        unsigned rA = (unsigned)__shfl_xor((int)sA, 32);
        unsigned rB = (unsigned)__shfl_xor((int)sB, 32);
        U8 f;
        f.u[0] = hi ? rA : P1a;
        f.u[1] = hi ? rB : P1b;
        f.u[2] = hi ? P2a : rA;
        f.u[3] = hi ? P2b : rB;
        B2[2 * c + h] = f;
      }
    }

    // GEMM2: K=128, 4 independent chains
    f32x16 a2[4];
    #pragma unroll
    for (int c = 0; c < 4; ++c) a2[c] = (f32x16)(0.f);
    #pragma unroll
    for (int c2 = 0; c2 < 4; ++c2)
      #pragma unroll
      for (int w = 0; w < 8; ++w)
        a2[c2] = __builtin_amdgcn_mfma_f32_32x32x16_bf16(A2[(c2 * 8 + w) * 64 + ln], B2[w].s, a2[c2], 0, 0, 0);

    // +b2, LN over 128 outcols (64 in-lane + partner)
    float vs = 0.f, vq = 0.f;
    #pragma unroll
    for (int c2 = 0; c2 < 4; ++c2) {
      #pragma unroll
      for (int q = 0; q < 4; ++q) {
        float4 b2q = *(const float4*)(eb2 + 32 * c2 + 8 * q + 4 * hi);
        #pragma unroll
        for (int i = 0; i < 4; ++i) {
          float x = a2[c2][q * 4 + i] + b2q[i];
          a2[c2][q * 4 + i] = x;
          vs += x; vq += x * x;
        }
      }
    }
    vs += __shfl_xor(vs, 32);
    vq += __shfl_xor(vq, 32);
    float mean = vs * (1.f / 128.f);
    float rstd = rsqrtf(vq * (1.f / 128.f) - mean * mean + 1e-5f);

    // LN scale/shift + ef residual, masked LDS scatter-add
    #pragma unroll
    for (int c2 = 0; c2 < 4; ++c2) {
      #pragma unroll
      for (int q = 0; q < 4; ++q) {
        int colb = 32 * c2 + 8 * q + 4 * hi;
        float4 g4 = *(const float4*)(elng + colb);
        float4 bb4 = *(const float4*)(elnb + colb);
        float4 e4 = *(const float4*)(rowE + colb);
        float v0 = e4.x + (a2[c2][q * 4 + 0] - mean) * rstd * g4.x + bb4.x;
        float v1 = e4.y + (a2[c2][q * 4 + 1] - mean) * rstd * g4.y + bb4.y;
        float v2 = e4.z + (a2[c2][q * 4 + 2] - mean) * rstd * g4.z + bb4.z;
        float v3 = e4.w + (a2[c2][q * 4 + 3] - mean) * rstd * g4.w + bb4.w;
        if (valid) {
          float* ap = &aggLDS[dl * 129 + colb];
          atomicAdd(ap + 0, v0);
          atomicAdd(ap + 1, v1);
          atomicAdd(ap + 2, v2);
          atomicAdd(ap + 3, v3);
        }
      }
    }
  }
  __syncthreads();

  // -------- node phase: all waves compute (redundant), each writes its quarter --------
  const short8* AN1 = (const short8*)(wp + WN1);
  const short8* AN2 = (const short8*)(wp + WN2);
  const float* rowG = gridf + (size_t)(n0 + l31) * HDIM;

  f32x16 a1[4];
  #pragma unroll
  for (int c = 0; c < 4; ++c) a1[c] = (f32x16)(0.f);
  #pragma unroll
  for (int ks = 0; ks < 16; ++ks) {
    short8 B;
    if (ks < 8) {
      B = cvt8(rowG + ks * 16 + hi * 8);
    } else {
      const float* ap = aggLDS + l31 * 129 + (ks - 8) * 16 + hi * 8;
      short8 t;
      #pragma unroll
      for (int i = 0; i < 8; ++i) t[i] = (short)f2bf_u(ap[i]);
      B = t;
    }
    #pragma unroll
    for (int c = 0; c < 4; ++c)
      a1[c] = __builtin_amdgcn_mfma_f32_32x32x16_bf16(AN1[(c * 16 + ks) * 64 + ln], B, a1[c], 0, 0, 0);
  }

  U8 B2[8];
  #pragma unroll
  for (int c = 0; c < 4; ++c) {
    #pragma unroll
    for (int q = 0; q < 4; ++q) {
      float4 b1q = *(const float4*)(nb1 + 32 * c + 8 * q + 4 * hi);
      #pragma unroll
      for (int i = 0; i < 4; ++i) {
        float x = a1[c][q * 4 + i] + b1q[i];
        a1[c][q * 4 + i] = x / (1.f + __expf(-x));
      }
    }
    #pragma unroll
    for (int h = 0; h < 2; ++h) {
      const f32x16& a = a1[c];
      unsigned P1a = pack2bf(a[8 * h + 0], a[8 * h + 1]);
      unsigned P1b = pack2bf(a[8 * h + 2], a[8 * h + 3]);
      unsigned P2a = pack2bf(a[8 * h + 4], a[8 * h + 5]);
      unsigned P2b = pack2bf(a[8 * h + 6], a[8 * h + 7]);
      unsigned sA = hi ? P1a : P2a, sB = hi ? P1b : P2b;
      unsigned rA = (unsigned)__shfl_xor((int)sA, 32);
      unsigned rB = (unsigned)__shfl_xor((int)sB, 32);
      U8 f;
      f.u[0] = hi ? rA : P1a;
      f.u[1] = hi ? rB : P1b;
      f.u[2] = hi ? P2a : rA;
      f.u[3] = hi ? P2b : rB;
      B2[2 * c + h] = f;
    }
  }

  f32x16 a2[4];
  #pragma unroll
  for (int c = 0; c < 4; ++c) a2[c] = (f32x16)(0.f);
  #pragma unroll
  for (int c2 = 0; c2 < 4; ++c2)
    #pragma unroll
    for (int w = 0; w < 8; ++w)
      a2[c2] = __builtin_amdgcn_mfma_f32_32x32x16_bf16(AN2[(c2 * 8 + w) * 64 + ln], B2[w].s, a2[c2], 0, 0, 0);

  float vs = 0.f, vq = 0.f;
  #pragma unroll
  for (int c2 = 0; c2 < 4; ++c2) {
    #pragma unroll
    for (int q = 0; q < 4; ++q) {
      float4 b2q = *(const float4*)(nb2 + 32 * c2 + 8 * q + 4 * hi);
      #pragma unroll
      for (int i = 0; i < 4; ++i) {
        float x = a2[c2][q * 4 + i] + b2q[i];
        a2[c2][q * 4 + i] = x;
        vs += x; vq += x * x;
      }
    }
  }
  vs += __shfl_xor(vs, 32);
  vq += __shfl_xor(vq, 32);
  float mean = vs * (1.f / 128.f);
  float rstd = rsqrtf(vq * (1.f / 128.f) - mean * mean + 1e-5f);

  #pragma unroll
  for (int c2 = 0; c2 < 4; ++c2) {
    if (c2 == wv) {
      #pragma unroll
      for (int q = 0; q < 4; ++q) {
        int colb = 32 * c2 + 8 * q + 4 * hi;
        float4 g4 = *(const float4*)(nlng + colb);
        float4 bb4 = *(const float4*)(nlnb + colb);
        float4 gr = *(const float4*)(rowG + colb);
        float4 res;
        res.x = gr.x + (a2[c2][q * 4 + 0] - mean) * rstd * g4.x + bb4.x;
        res.y = gr.y + (a2[c2][q * 4 + 1] - mean) * rstd * g4.y + bb4.y;
        res.z = gr.z + (a2[c2][q * 4 + 2] - mean) * rstd * g4.z + bb4.z;
        res.w = gr.w + (a2[c2][q * 4 + 3] - mean) * rstd * g4.w + bb4.w;
        *(float4*)(out + (size_t)(n0 + l31) * HDIM + colb) = res;
      }
    }
  }
}

extern "C" void kernel_launch(void* const* d_in, const int* in_sizes, int n_in,
                              void* d_out, int out_size, void* d_ws, size_t ws_size,
                              hipStream_t stream)
{
  (void)in_sizes; (void)n_in; (void)out_size; (void)ws_size;
  const float* ef   = (const float*)d_in[0];
  const float* grid = (const float*)d_in[1];
  const float* mesh = (const float*)d_in[2];
  const float* eW1  = (const float*)d_in[3];
  const float* eb1  = (const float*)d_in[4];
  const float* eW2  = (const float*)d_in[5];
  const float* eb2  = (const float*)d_in[6];
  const float* elng = (const float*)d_in[7];
  const float* elnb = (const float*)d_in[8];
  const float* nW1  = (const float*)d_in[9];
  const float* nb1  = (const float*)d_in[10];
  const float* nW2  = (const float*)d_in[11];
  const float* nb2  = (const float*)d_in[12];
  const float* nlng = (const float*)d_in[13];
  const float* nlnb = (const float*)d_in[14];
  const int* src    = (const int*)d_in[15];
  const int* dst    = (const int*)d_in[16];
  float* out = (float*)d_out;

  unsigned char* wsb = (unsigned char*)d_ws;
  u32* cnt  = (u32*)(wsb + WS_COUNT);
  u32* rp   = (u32*)(wsb + WS_ROWPTR);
  u32* wloc = (u32*)(wsb + WS_WLOC);
  u32* bsum = (u32*)(wsb + WS_BSUM);
  u64* sorted = (u64*)(wsb + WS_SORTED);
  unsigned short* wp = (unsigned short*)(wsb + WS_WEIGHTS);

  hipMemsetAsync(cnt, 0, (size_t)NGRID * 4, stream);
  pack_weights<<<448, 256, 0, stream>>>(eW1, eW2, nW1, nW2, wp);
  hist_k<<<NEDGE / 256, 256, 0, stream>>>(dst, cnt);
  scan1<<<256, 256, 0, stream>>>(cnt, rp, bsum);
  scan2<<<1, 256, 0, stream>>>(bsum);
  scan3<<<256, 256, 0, stream>>>(rp, wloc, bsum);
  scatter_k<<<NEDGE / 256, 256, 0, stream>>>(src, dst, wloc, sorted);
  fused_kernel<<<NGRID / 32, 256, 0, stream>>>(ef, grid, mesh, wp,
      eb1, eb2, elng, elnb, nb1, nb2, nlng, nlnb, rp, sorted, out);
}

// Round 6
// 1797.684 us; speedup vs baseline: 1.5387x; 1.5387x over previous
//
#include <hip/hip_runtime.h>
#include <stdint.h>

#define HDIM 128
#define NGRID 262144
#define NMESH 40962
#define NEDGE 524288

typedef __attribute__((ext_vector_type(8))) short short8;
typedef __attribute__((ext_vector_type(16))) float f32x16;
typedef unsigned int u32;
typedef unsigned long long u64;

// ---- ws layout (byte offsets) ----
#define WS_COUNT   0x000000u
#define WS_ROWPTR  0x100000u
#define WS_WLOC    0x200010u
#define WS_BSUM    0x300100u
#define WS_SORTED  0x310000u
#define WS_WEIGHTS 0x800000u
// weight section offsets in u16 units:
#define WE1 0u
#define WE2 49152u
#define WN1 65536u
#define WN2 98304u

static __device__ __forceinline__ u32 f2bf_u(float f) {
  union { float f; u32 u; } v; v.f = f;
  u32 u = v.u;
  u += 0x7fffu + ((u >> 16) & 1u);
  return u >> 16;
}
static __device__ __forceinline__ unsigned short f2bf(float f) { return (unsigned short)f2bf_u(f); }
static __device__ __forceinline__ u32 pack2bf(float a, float b) {
  return f2bf_u(a) | (f2bf_u(b) << 16);
}
static __device__ __forceinline__ short8 cvt8(const float* p) {
  float4 f0 = *(const float4*)p;
  float4 f1 = *(const float4*)(p + 4);
  short8 r;
  r[0] = (short)f2bf_u(f0.x); r[1] = (short)f2bf_u(f0.y);
  r[2] = (short)f2bf_u(f0.z); r[3] = (short)f2bf_u(f0.w);
  r[4] = (short)f2bf_u(f1.x); r[5] = (short)f2bf_u(f1.y);
  r[6] = (short)f2bf_u(f1.z); r[7] = (short)f2bf_u(f1.w);
  return r;
}

union U8 { unsigned int u[4]; short8 s; };

// ---- pack weights frag-major for 32x32x16: frag (w,ks), lane-contiguous 16B ----
__global__ void pack_weights(const float* __restrict__ eW1, const float* __restrict__ eW2,
                             const float* __restrict__ nW1, const float* __restrict__ nW2,
                             unsigned short* __restrict__ wp)
{
  int i = blockIdx.x * 256 + threadIdx.x;
  const float* W; int KS; u32 base; int j;
  if (i < 49152)       { W = eW1; KS = 24; base = WE1; j = i; }
  else if (i < 65536)  { W = eW2; KS = 8;  base = WE2; j = i - 49152; }
  else if (i < 98304)  { W = nW1; KS = 16; base = WN1; j = i - 65536; }
  else if (i < 114688) { W = nW2; KS = 8;  base = WN2; j = i - 98304; }
  else return;
  int ii = j & 7, l = (j >> 3) & 63, frag = j >> 9;
  int ks = frag % KS, w = frag / KS;
  int row = w * 32 + (l & 31);
  int k = ks * 16 + (l >> 5) * 8 + ii;
  wp[base + j] = f2bf(W[(size_t)k * 128 + row]);
}

__global__ void hist_k(const int* __restrict__ dst, u32* __restrict__ cnt) {
  int e = blockIdx.x * 256 + threadIdx.x;
  atomicAdd(&cnt[dst[e]], 1u);
}

__global__ void scan1(const u32* __restrict__ cnt, u32* __restrict__ rp, u32* __restrict__ bsum) {
  int t = threadIdx.x, b = blockIdx.x;
  int i0 = b * 1024 + t * 4;
  uint4 v = *(const uint4*)(cnt + i0);
  u32 s = v.x + v.y + v.z + v.w;
  u32 sc = s;
  #pragma unroll
  for (int d = 1; d < 64; d <<= 1) {
    u32 n = (u32)__shfl_up((int)sc, d);
    if ((t & 63) >= d) sc += n;
  }
  __shared__ u32 wsum[4];
  if ((t & 63) == 63) wsum[t >> 6] = sc;
  __syncthreads();
  u32 woff = 0;
  for (int w = 0; w < (t >> 6); ++w) woff += wsum[w];
  u32 ex = woff + sc - s;
  rp[i0] = ex; rp[i0 + 1] = ex + v.x; rp[i0 + 2] = ex + v.x + v.y; rp[i0 + 3] = ex + v.x + v.y + v.z;
  if (t == 255) bsum[b] = woff + sc;
}

__global__ void scan2(u32* __restrict__ bsum) {
  int t = threadIdx.x;
  u32 s = bsum[t];
  u32 sc = s;
  #pragma unroll
  for (int d = 1; d < 64; d <<= 1) {
    u32 n = (u32)__shfl_up((int)sc, d);
    if ((t & 63) >= d) sc += n;
  }
  __shared__ u32 wsum[4];
  if ((t & 63) == 63) wsum[t >> 6] = sc;
  __syncthreads();
  u32 woff = 0;
  for (int w = 0; w < (t >> 6); ++w) woff += wsum[w];
  bsum[t] = woff + sc - s;
}

__global__ void scan3(u32* __restrict__ rp, u32* __restrict__ wloc, const u32* __restrict__ bsum) {
  int t = threadIdx.x, b = blockIdx.x;
  int i0 = b * 1024 + t * 4;
  u32 off = bsum[b];
  #pragma unroll
  for (int j = 0; j < 4; ++j) { u32 vv = rp[i0 + j] + off; rp[i0 + j] = vv; wloc[i0 + j] = vv; }
  if (b == 0 && t == 0) rp[NGRID] = NEDGE;
}

__global__ void scatter_k(const int* __restrict__ src, const int* __restrict__ dst,
                          u32* __restrict__ wloc, u64* __restrict__ sorted) {
  int e = blockIdx.x * 256 + threadIdx.x;
  int d = dst[e];
  u32 pos = atomicAdd(&wloc[d], 1u);
  sorted[pos] = (u64)(u32)src[e] | ((u64)(u32)d << 16) | ((u64)(u32)e << 34);
}

// ---- fused: block = 128 grid nodes; each wave owns 32 nodes + their edges.
//      Fully wave-private: private agg slice, ZERO barriers, no redundant compute. ----
__global__ __launch_bounds__(256, 2)
void fused_kernel(const float* __restrict__ ef, const float* __restrict__ gridf,
                  const float* __restrict__ mesh,
                  const unsigned short* __restrict__ wp,
                  const float* __restrict__ eb1, const float* __restrict__ eb2,
                  const float* __restrict__ elng, const float* __restrict__ elnb,
                  const float* __restrict__ nb1, const float* __restrict__ nb2,
                  const float* __restrict__ nlng, const float* __restrict__ nlnb,
                  const u32* __restrict__ rowptr, const u64* __restrict__ sorted,
                  float* __restrict__ out)
{
  __shared__ float aggLDS[4][32 * 129];   // 66 KB; one 16.5 KB slice per wave

  const int tid = threadIdx.x;
  const int wv = tid >> 6, ln = tid & 63, l31 = ln & 31, hi = ln >> 5;
  const int nb = blockIdx.x * 128 + wv * 32;        // wave's first node
  const int rs = (int)rowptr[nb], re = (int)rowptr[nb + 32];
  float* aggw = aggLDS[wv];

  // zero the wave-private agg slice (no barrier needed: wave-private)
  for (int i = ln; i < 32 * 129; i += 64) aggw[i] = 0.f;

  const short8* A1 = (const short8*)(wp + WE1);
  const short8* A2 = (const short8*)(wp + WE2);

  // -------- edge loop: wave-private 32-edge tiles --------
  for (int base = rs; base < re; base += 32) {
    int p = base + l31;
    const bool valid = p < re;
    if (!valid) p = re - 1;
    const u64 sv = sorted[p];
    const int dl = (int)((sv >> 16) & 0x3ffffu) - nb;
    const float* rowS = mesh  + (size_t)(sv & 0xffffu) * HDIM;
    const float* rowD = gridf + (size_t)(nb + dl) * HDIM;
    const float* rowE = ef    + (size_t)(sv >> 34) * HDIM;

    // GEMM1: h1[128 cols x 32 edges], K=384, 4 independent chains
    f32x16 a1[4];
    #pragma unroll
    for (int c = 0; c < 4; ++c) a1[c] = (f32x16)(0.f);
    #pragma unroll
    for (int ks = 0; ks < 24; ++ks) {
      const float* bp = (ks < 8) ? (rowS + ks * 16)
                      : (ks < 16) ? (rowD + (ks - 8) * 16)
                                  : (rowE + (ks - 16) * 16);
      short8 B = cvt8(bp + hi * 8);
      #pragma unroll
      for (int c = 0; c < 4; ++c)
        a1[c] = __builtin_amdgcn_mfma_f32_32x32x16_bf16(A1[(c * 24 + ks) * 64 + ln], B, a1[c], 0, 0, 0);
    }

    // silu(x+b1) then pack to GEMM2 B-frags (in-register, shfl pair-exchange)
    U8 B2[8];
    #pragma unroll
    for (int c = 0; c < 4; ++c) {
      #pragma unroll
      for (int q = 0; q < 4; ++q) {
        float4 b1q = *(const float4*)(eb1 + 32 * c + 8 * q + 4 * hi);
        #pragma unroll
        for (int i = 0; i < 4; ++i) {
          float x = a1[c][q * 4 + i] + b1q[i];
          a1[c][q * 4 + i] = x / (1.f + __expf(-x));
        }
      }
      #pragma unroll
      for (int h = 0; h < 2; ++h) {
        const f32x16& a = a1[c];
        unsigned P1a = pack2bf(a[8 * h + 0], a[8 * h + 1]);
        unsigned P1b = pack2bf(a[8 * h + 2], a[8 * h + 3]);
        unsigned P2a = pack2bf(a[8 * h + 4], a[8 * h + 5]);
        unsigned P2b = pack2bf(a[8 * h + 6], a[8 * h + 7]);
        unsigned sA = hi ? P1a : P2a, sB = hi ? P1b : P2b;
        unsigned rA = (unsigned)__shfl_xor((int)sA, 32);
        unsigned rB = (unsigned)__shfl_xor((int)sB, 32);
        U8 f;
        f.u[0] = hi ? rA : P1a;
        f.u[1] = hi ? rB : P1b;
        f.u[2] = hi ? P2a : rA;
        f.u[3] = hi ? P2b : rB;
        B2[2 * c + h] = f;
      }
    }

    // GEMM2: K=128, 4 independent chains
    f32x16 a2[4];
    #pragma unroll
    for (int c = 0; c < 4; ++c) a2[c] = (f32x16)(0.f);
    #pragma unroll
    for (int c2 = 0; c2 < 4; ++c2)
      #pragma unroll
      for (int w = 0; w < 8; ++w)
        a2[c2] = __builtin_amdgcn_mfma_f32_32x32x16_bf16(A2[(c2 * 8 + w) * 64 + ln], B2[w].s, a2[c2], 0, 0, 0);

    // +b2, LN over 128 outcols (64 in-lane + partner)
    float vs = 0.f, vq = 0.f;
    #pragma unroll
    for (int c2 = 0; c2 < 4; ++c2) {
      #pragma unroll
      for (int q = 0; q < 4; ++q) {
        float4 b2q = *(const float4*)(eb2 + 32 * c2 + 8 * q + 4 * hi);
        #pragma unroll
        for (int i = 0; i < 4; ++i) {
          float x = a2[c2][q * 4 + i] + b2q[i];
          a2[c2][q * 4 + i] = x;
          vs += x; vq += x * x;
        }
      }
    }
    vs += __shfl_xor(vs, 32);
    vq += __shfl_xor(vq, 32);
    float mean = vs * (1.f / 128.f);
    float rstd = rsqrtf(vq * (1.f / 128.f) - mean * mean + 1e-5f);

    // LN scale/shift + ef residual, masked wave-private LDS scatter-add
    #pragma unroll
    for (int c2 = 0; c2 < 4; ++c2) {
      #pragma unroll
      for (int q = 0; q < 4; ++q) {
        int colb = 32 * c2 + 8 * q + 4 * hi;
        float4 g4 = *(const float4*)(elng + colb);
        float4 bb4 = *(const float4*)(elnb + colb);
        float4 e4 = *(const float4*)(rowE + colb);
        float v0 = e4.x + (a2[c2][q * 4 + 0] - mean) * rstd * g4.x + bb4.x;
        float v1 = e4.y + (a2[c2][q * 4 + 1] - mean) * rstd * g4.y + bb4.y;
        float v2 = e4.z + (a2[c2][q * 4 + 2] - mean) * rstd * g4.z + bb4.z;
        float v3 = e4.w + (a2[c2][q * 4 + 3] - mean) * rstd * g4.w + bb4.w;
        if (valid) {
          float* ap = &aggw[dl * 129 + colb];
          atomicAdd(ap + 0, v0);
          atomicAdd(ap + 1, v1);
          atomicAdd(ap + 2, v2);
          atomicAdd(ap + 3, v3);
        }
      }
    }
  }

  // -------- node phase: wave-private 32 nodes, no redundancy, no barrier --------
  const short8* AN1 = (const short8*)(wp + WN1);
  const short8* AN2 = (const short8*)(wp + WN2);
  const float* rowG = gridf + (size_t)(nb + l31) * HDIM;

  f32x16 a1[4];
  #pragma unroll
  for (int c = 0; c < 4; ++c) a1[c] = (f32x16)(0.f);
  #pragma unroll
  for (int ks = 0; ks < 16; ++ks) {
    short8 B;
    if (ks < 8) {
      B = cvt8(rowG + ks * 16 + hi * 8);
    } else {
      const float* ap = aggw + l31 * 129 + (ks - 8) * 16 + hi * 8;
      short8 t;
      #pragma unroll
      for (int i = 0; i < 8; ++i) t[i] = (short)f2bf_u(ap[i]);
      B = t;
    }
    #pragma unroll
    for (int c = 0; c < 4; ++c)
      a1[c] = __builtin_amdgcn_mfma_f32_32x32x16_bf16(AN1[(c * 16 + ks) * 64 + ln], B, a1[c], 0, 0, 0);
  }

  U8 B2[8];
  #pragma unroll
  for (int c = 0; c < 4; ++c) {
    #pragma unroll
    for (int q = 0; q < 4; ++q) {
      float4 b1q = *(const float4*)(nb1 + 32 * c + 8 * q + 4 * hi);
      #pragma unroll
      for (int i = 0; i < 4; ++i) {
        float x = a1[c][q * 4 + i] + b1q[i];
        a1[c][q * 4 + i] = x / (1.f + __expf(-x));
      }
    }
    #pragma unroll
    for (int h = 0; h < 2; ++h) {
      const f32x16& a = a1[c];
      unsigned P1a = pack2bf(a[8 * h + 0], a[8 * h + 1]);
      unsigned P1b = pack2bf(a[8 * h + 2], a[8 * h + 3]);
      unsigned P2a = pack2bf(a[8 * h + 4], a[8 * h + 5]);
      unsigned P2b = pack2bf(a[8 * h + 6], a[8 * h + 7]);
      unsigned sA = hi ? P1a : P2a, sB = hi ? P1b : P2b;
      unsigned rA = (unsigned)__shfl_xor((int)sA, 32);
      unsigned rB = (unsigned)__shfl_xor((int)sB, 32);
      U8 f;
      f.u[0] = hi ? rA : P1a;
      f.u[1] = hi ? rB : P1b;
      f.u[2] = hi ? P2a : rA;
      f.u[3] = hi ? P2b : rB;
      B2[2 * c + h] = f;
    }
  }

  f32x16 a2[4];
  #pragma unroll
  for (int c = 0; c < 4; ++c) a2[c] = (f32x16)(0.f);
  #pragma unroll
  for (int c2 = 0; c2 < 4; ++c2)
    #pragma unroll
    for (int w = 0; w < 8; ++w)
      a2[c2] = __builtin_amdgcn_mfma_f32_32x32x16_bf16(AN2[(c2 * 8 + w) * 64 + ln], B2[w].s, a2[c2], 0, 0, 0);

  float vs = 0.f, vq = 0.f;
  #pragma unroll
  for (int c2 = 0; c2 < 4; ++c2) {
    #pragma unroll
    for (int q = 0; q < 4; ++q) {
      float4 b2q = *(const float4*)(nb2 + 32 * c2 + 8 * q + 4 * hi);
      #pragma unroll
      for (int i = 0; i < 4; ++i) {
        float x = a2[c2][q * 4 + i] + b2q[i];
        a2[c2][q * 4 + i] = x;
        vs += x; vq += x * x;
      }
    }
  }
  vs += __shfl_xor(vs, 32);
  vq += __shfl_xor(vq, 32);
  float mean = vs * (1.f / 128.f);
  float rstd = rsqrtf(vq * (1.f / 128.f) - mean * mean + 1e-5f);

  #pragma unroll
  for (int c2 = 0; c2 < 4; ++c2) {
    #pragma unroll
    for (int q = 0; q < 4; ++q) {
      int colb = 32 * c2 + 8 * q + 4 * hi;
      float4 g4 = *(const float4*)(nlng + colb);
      float4 bb4 = *(const float4*)(nlnb + colb);
      float4 gr = *(const float4*)(rowG + colb);
      float4 res;
      res.x = gr.x + (a2[c2][q * 4 + 0] - mean) * rstd * g4.x + bb4.x;
      res.y = gr.y + (a2[c2][q * 4 + 1] - mean) * rstd * g4.y + bb4.y;
      res.z = gr.z + (a2[c2][q * 4 + 2] - mean) * rstd * g4.z + bb4.z;
      res.w = gr.w + (a2[c2][q * 4 + 3] - mean) * rstd * g4.w + bb4.w;
      *(float4*)(out + (size_t)(nb + l31) * HDIM + colb) = res;
    }
  }
}

extern "C" void kernel_launch(void* const* d_in, const int* in_sizes, int n_in,
                              void* d_out, int out_size, void* d_ws, size_t ws_size,
                              hipStream_t stream)
{
  (void)in_sizes; (void)n_in; (void)out_size; (void)ws_size;
  const float* ef   = (const float*)d_in[0];
  const float* grid = (const float*)d_in[1];
  const float* mesh = (const float*)d_in[2];
  const float* eW1  = (const float*)d_in[3];
  const float* eb1  = (const float*)d_in[4];
  const float* eW2  = (const float*)d_in[5];
  const float* eb2  = (const float*)d_in[6];
  const float* elng = (const float*)d_in[7];
  const float* elnb = (const float*)d_in[8];
  const float* nW1  = (const float*)d_in[9];
  const float* nb1  = (const float*)d_in[10];
  const float* nW2  = (const float*)d_in[11];
  const float* nb2  = (const float*)d_in[12];
  const float* nlng = (const float*)d_in[13];
  const float* nlnb = (const float*)d_in[14];
  const int* src    = (const int*)d_in[15];
  const int* dst    = (const int*)d_in[16];
  float* out = (float*)d_out;

  unsigned char* wsb = (unsigned char*)d_ws;
  u32* cnt  = (u32*)(wsb + WS_COUNT);
  u32* rp   = (u32*)(wsb + WS_ROWPTR);
  u32* wloc = (u32*)(wsb + WS_WLOC);
  u32* bsum = (u32*)(wsb + WS_BSUM);
  u64* sorted = (u64*)(wsb + WS_SORTED);
  unsigned short* wp = (unsigned short*)(wsb + WS_WEIGHTS);

  hipMemsetAsync(cnt, 0, (size_t)NGRID * 4, stream);
  pack_weights<<<448, 256, 0, stream>>>(eW1, eW2, nW1, nW2, wp);
  hist_k<<<NEDGE / 256, 256, 0, stream>>>(dst, cnt);
  scan1<<<256, 256, 0, stream>>>(cnt, rp, bsum);
  scan2<<<1, 256, 0, stream>>>(bsum);
  scan3<<<256, 256, 0, stream>>>(rp, wloc, bsum);
  scatter_k<<<NEDGE / 256, 256, 0, stream>>>(src, dst, wloc, sorted);
  fused_kernel<<<NGRID / 128, 256, 0, stream>>>(ef, grid, mesh, wp,
      eb1, eb2, elng, elnb, nb1, nb2, nlng, nlnb, rp, sorted, out);
}